// Round 1
// baseline (309.963 us; speedup 1.0000x reference)
//
#include <hip/hip_runtime.h>
#include <stdint.h>

#define NG   64      // graphs
#define N0   1024    // nodes layer 1
#define DD   128     // feature dim
#define NE   16384   // edges per graph
#define NOUT 64      // output dim

__device__ __forceinline__ float waveReduceSum(float v) {
    // full 64-lane reduction
    for (int off = 32; off > 0; off >>= 1) v += __shfl_xor(v, off, 64);
    return v;
}

// ---------------------------------------------------------------------------
// Kernel 1: per-node dot products s_rel[n] = x[n].w_rel, s_root[n] = x[n].w_root
// One wave per node (lane l handles dims 2l, 2l+1), 4 nodes per wave.
// x: (totalNodes, D) contiguous, totalNodes = G*n
// ---------------------------------------------------------------------------
__global__ __launch_bounds__(256) void dots_kernel(
    const float* __restrict__ x,
    const float* __restrict__ w_rel, const float* __restrict__ w_root,
    float* __restrict__ s_rel, float* __restrict__ s_root,
    int totalNodes)
{
    int wave = blockIdx.x * (blockDim.x >> 6) + (threadIdx.x >> 6);
    int lane = threadIdx.x & 63;
    float wr0 = w_rel[lane * 2],  wr1 = w_rel[lane * 2 + 1];
    float wo0 = w_root[lane * 2], wo1 = w_root[lane * 2 + 1];
    #pragma unroll
    for (int t = 0; t < 4; ++t) {
        int node = wave * 4 + t;
        if (node >= totalNodes) return;
        const float2 v = *(const float2*)(x + (size_t)node * DD + lane * 2);
        float pr = v.x * wr0 + v.y * wr1;
        float po = v.x * wo0 + v.y * wo1;
        pr = waveReduceSum(pr);
        po = waveReduceSum(po);
        if (lane == 0) { s_rel[node] = pr; s_root[node] = po; }
    }
}

// ---------------------------------------------------------------------------
// Kernel 3: fused gather (new_x = x[perm]*score) + next-layer dots.
// Output nodes j in [0, G*k); x1[j] = x0[g, perm[j]] * tops[j]
// ---------------------------------------------------------------------------
__global__ __launch_bounds__(256) void gather_dots_kernel(
    const float* __restrict__ x0,       // (G, nIn, D)
    const int*   __restrict__ perm,     // (G, k)
    const float* __restrict__ tops,     // (G, k)
    const float* __restrict__ w_rel, const float* __restrict__ w_root,
    float* __restrict__ x1,             // (G, k, D)
    float* __restrict__ s_rel, float* __restrict__ s_root,  // (G*k)
    int nIn, int k, int totalOut)
{
    int wave = blockIdx.x * (blockDim.x >> 6) + (threadIdx.x >> 6);
    int lane = threadIdx.x & 63;
    float wr0 = w_rel[lane * 2],  wr1 = w_rel[lane * 2 + 1];
    float wo0 = w_root[lane * 2], wo1 = w_root[lane * 2 + 1];
    #pragma unroll
    for (int t = 0; t < 4; ++t) {
        int j = wave * 4 + t;
        if (j >= totalOut) return;
        int g  = j / k;
        int node = perm[j];
        float sc = tops[j];
        const float2 v0 = *(const float2*)(x0 + ((size_t)g * nIn + node) * DD + lane * 2);
        float2 v; v.x = v0.x * sc; v.y = v0.y * sc;
        *(float2*)(x1 + (size_t)j * DD + lane * 2) = v;
        float pr = v.x * wr0 + v.y * wr1;
        float po = v.x * wo0 + v.y * wo1;
        pr = waveReduceSum(pr);
        po = waveReduceSum(po);
        if (lane == 0) { s_rel[j] = pr; s_root[j] = po; }
    }
}

// ---------------------------------------------------------------------------
// Kernel 2/4: per-graph attn scatter + score + top-k (bitonic) + edge remap.
// One block (256 threads) per graph. maskIn == nullptr => all edges valid.
// srcOut == nullptr => last layer, skip edge remap.
// ---------------------------------------------------------------------------
__global__ __launch_bounds__(256) void graph_kernel(
    const float* __restrict__ s_rel_g,   // (G*n)
    const float* __restrict__ s_root_g,  // (G*n)
    const float* __restrict__ b_rel_p,   // scalar for this layer
    const float* __restrict__ w_sel_p,   // scalar for this layer
    const int*   __restrict__ srcIn,     // + g*gStride
    const int*   __restrict__ dstIn,     // + g*gStride
    const int*   __restrict__ maskIn,    // (G, E) or null
    long gStrideIn,
    int n, int k,
    int*   __restrict__ permOut,         // (G, k)
    float* __restrict__ topsOut,         // (G, k)
    int*   __restrict__ srcOut,          // (G, E) or null
    int*   __restrict__ dstOut,
    int*   __restrict__ maskOut)
{
    __shared__ float attn[N0];
    __shared__ float srel[N0];
    __shared__ unsigned long long keys[N0];
    __shared__ int newidx[N0];

    const int g = blockIdx.x, tid = threadIdx.x;
    const float* sr = s_rel_g  + (size_t)g * n;
    const float* so = s_root_g + (size_t)g * n;
    const float brel = *b_rel_p;
    const float sgn  = (*w_sel_p >= 0.f) ? 1.f : -1.f;

    for (int i = tid; i < n; i += 256) { srel[i] = sr[i]; attn[i] = so[i] + brel; }
    __syncthreads();

    const int* src = srcIn + (size_t)g * gStrideIn;
    const int* dst = dstIn + (size_t)g * gStrideIn;
    const int* msk = maskIn ? (maskIn + (size_t)g * NE) : nullptr;
    for (int e = tid; e < NE; e += 256) {
        if (!msk || msk[e]) atomicAdd(&attn[dst[e]], srel[src[e]]);
    }
    __syncthreads();

    // score -> sortable key: (monotone u32 of score) << 32 | (n-1-idx)
    // descending sort => score desc, idx asc on ties (matches jax.lax.top_k)
    for (int i = tid; i < n; i += 256) {
        float sc = tanhf(attn[i] * sgn);
        unsigned int u = __float_as_uint(sc);
        u = (u & 0x80000000u) ? ~u : (u | 0x80000000u);
        keys[i] = ((unsigned long long)u << 32) | (unsigned int)(n - 1 - i);
    }
    __syncthreads();

    // bitonic sort, descending
    for (int k2 = 2; k2 <= n; k2 <<= 1) {
        for (int j = k2 >> 1; j > 0; j >>= 1) {
            for (int i = tid; i < n; i += 256) {
                int ixj = i ^ j;
                if (ixj > i) {
                    unsigned long long a = keys[i], b = keys[ixj];
                    bool up = ((i & k2) == 0);
                    if (up ? (a < b) : (a > b)) { keys[i] = b; keys[ixj] = a; }
                }
            }
            __syncthreads();
        }
    }

    for (int i = tid; i < n; i += 256) newidx[i] = -1;
    __syncthreads();

    for (int j = tid; j < k; j += 256) {
        unsigned long long key = keys[j];
        int idx = (n - 1) - (int)(key & 0xffffffffu);
        unsigned int u = (unsigned int)(key >> 32);
        unsigned int fb = (u & 0x80000000u) ? (u ^ 0x80000000u) : ~u;
        permOut[(size_t)g * k + j] = idx;
        topsOut[(size_t)g * k + j] = __uint_as_float(fb);
        newidx[idx] = j;
    }
    __syncthreads();

    if (srcOut) {
        for (int e = tid; e < NE; e += 256) {
            int valid = (!msk || msk[e]);
            int s2 = valid ? newidx[src[e]] : -1;
            int d2 = valid ? newidx[dst[e]] : -1;
            int m = (s2 >= 0) && (d2 >= 0);
            srcOut[(size_t)g * NE + e]  = m ? s2 : 0;
            dstOut[(size_t)g * NE + e]  = m ? d2 : 0;
            maskOut[(size_t)g * NE + e] = m;
        }
    }
}

// ---------------------------------------------------------------------------
// Kernel 5: readout = concat(mean, max) @ W_lin + b_lin, fused with the
// final gather (new_x2 = x1[perm2]*tops2 is never materialized).
// One block (256 threads) per graph.
// ---------------------------------------------------------------------------
__global__ __launch_bounds__(256) void readout_kernel(
    const float* __restrict__ x1,     // (G, 512, D)
    const int*   __restrict__ perm2,  // (G, 256)
    const float* __restrict__ tops2,  // (G, 256)
    const float* __restrict__ W_lin,  // (2D, OUT)
    const float* __restrict__ b_lin,  // (OUT)
    float* __restrict__ out)          // (G, OUT)
{
    __shared__ float r[2 * DD];
    __shared__ float s0[256], m0[256];
    const int g = blockIdx.x, tid = threadIdx.x;
    const int d = tid & (DD - 1);
    const int half = tid >> 7;           // 0 or 1
    const int* pp = perm2 + (size_t)g * 256;
    const float* tt = tops2 + (size_t)g * 256;

    float sum = 0.f, mx = -3.0e38f;
    for (int j = half * 128; j < half * 128 + 128; ++j) {
        int node = pp[j];
        float sc = tt[j];
        float v = x1[((size_t)g * 512 + node) * DD + d] * sc;
        sum += v;
        mx = fmaxf(mx, v);
    }
    s0[tid] = sum; m0[tid] = mx;
    __syncthreads();
    if (tid < 128) {
        r[tid]       = (s0[tid] + s0[tid + 128]) * (1.f / 256.f);
        r[tid + 128] = fmaxf(m0[tid], m0[tid + 128]);
    }
    __syncthreads();
    if (tid < NOUT) {
        float acc = b_lin[tid];
        #pragma unroll 8
        for (int i = 0; i < 2 * DD; ++i) acc += r[i] * W_lin[i * NOUT + tid];
        out[(size_t)g * NOUT + tid] = acc;
    }
}

// ---------------------------------------------------------------------------
extern "C" void kernel_launch(void* const* d_in, const int* in_sizes, int n_in,
                              void* d_out, int out_size, void* d_ws, size_t ws_size,
                              hipStream_t stream)
{
    const float* x0     = (const float*)d_in[0];  // (G, 1024, 128)
    const int*   ei     = (const int*)  d_in[1];  // (G, 2, E)
    const float* w_rel  = (const float*)d_in[2];  // (2, 128)
    const float* b_rel  = (const float*)d_in[3];  // (2,)
    const float* w_root = (const float*)d_in[4];  // (2, 128)
    const float* w_sel  = (const float*)d_in[5];  // (2,)
    const float* W_lin  = (const float*)d_in[6];  // (256, 64)
    const float* b_lin  = (const float*)d_in[7];  // (64,)
    float* out = (float*)d_out;

    char* ws = (char*)d_ws;
    size_t off = 0;
    auto alloc = [&](size_t bytes) -> void* {
        off = (off + 255) & ~(size_t)255;
        void* p = ws + off;
        off += bytes;
        return p;
    };

    float* s_rel1  = (float*)alloc((size_t)NG * N0 * 4);
    float* s_root1 = (float*)alloc((size_t)NG * N0 * 4);
    int*   perm1   = (int*)  alloc((size_t)NG * 512 * 4);
    float* tops1   = (float*)alloc((size_t)NG * 512 * 4);
    int*   src2    = (int*)  alloc((size_t)NG * NE * 4);
    int*   dst2    = (int*)  alloc((size_t)NG * NE * 4);
    int*   mask2   = (int*)  alloc((size_t)NG * NE * 4);
    float* x1      = (float*)alloc((size_t)NG * 512 * DD * 4);
    float* s_rel2  = (float*)alloc((size_t)NG * 512 * 4);
    float* s_root2 = (float*)alloc((size_t)NG * 512 * 4);
    int*   perm2   = (int*)  alloc((size_t)NG * 256 * 4);
    float* tops2   = (float*)alloc((size_t)NG * 256 * 4);
    (void)ws_size; (void)in_sizes; (void)n_in; (void)out_size;

    // ---- Layer 1 ----
    {
        int total = NG * N0;                         // 65536 nodes
        dots_kernel<<<total / 16, 256, 0, stream>>>(
            x0, w_rel + 0 * DD, w_root + 0 * DD, s_rel1, s_root1, total);

        graph_kernel<<<NG, 256, 0, stream>>>(
            s_rel1, s_root1, b_rel + 0, w_sel + 0,
            ei, ei + NE, /*maskIn=*/nullptr, /*gStride=*/(long)(2 * NE),
            /*n=*/N0, /*k=*/512,
            perm1, tops1, src2, dst2, mask2);
    }

    // ---- Layer 2 ----
    {
        int total = NG * 512;                        // 32768 output nodes
        gather_dots_kernel<<<total / 16, 256, 0, stream>>>(
            x0, perm1, tops1, w_rel + 1 * DD, w_root + 1 * DD,
            x1, s_rel2, s_root2, /*nIn=*/N0, /*k=*/512, total);

        graph_kernel<<<NG, 256, 0, stream>>>(
            s_rel2, s_root2, b_rel + 1, w_sel + 1,
            src2, dst2, mask2, /*gStride=*/(long)NE,
            /*n=*/512, /*k=*/256,
            perm2, tops2, /*srcOut=*/nullptr, nullptr, nullptr);
    }

    // ---- Readout ----
    readout_kernel<<<NG, 256, 0, stream>>>(x1, perm2, tops2, W_lin, b_lin, out);
}

// Round 2
// 193.811 us; speedup vs baseline: 1.5993x; 1.5993x over previous
//
#include <hip/hip_runtime.h>
#include <stdint.h>

#define NG   64      // graphs
#define N0   1024    // nodes layer 1
#define N1   512     // nodes layer 2
#define DD   128     // feature dim
#define NE   16384   // edges per graph
#define NOUT 64      // output dim

__device__ __forceinline__ float waveReduceSum(float v) {
    for (int off = 32; off > 0; off >>= 1) v += __shfl_xor(v, off, 64);
    return v;
}

// ---------------------------------------------------------------------------
// Kernel 1: per-node dots. s_rel[n] = x[n].w_rel ; attn[n] = x[n].w_root + b.
// One wave per 4 consecutive nodes (lane l covers dims 2l, 2l+1).
// ---------------------------------------------------------------------------
__global__ __launch_bounds__(256) void dots1_kernel(
    const float* __restrict__ x,
    const float* __restrict__ w_rel, const float* __restrict__ w_root,
    const float* __restrict__ b_rel_p,
    float* __restrict__ s_rel, float* __restrict__ attn,
    int totalNodes)
{
    int wave = blockIdx.x * 4 + (threadIdx.x >> 6);
    int lane = threadIdx.x & 63;
    float wr0 = w_rel[lane * 2],  wr1 = w_rel[lane * 2 + 1];
    float wo0 = w_root[lane * 2], wo1 = w_root[lane * 2 + 1];
    float brel = *b_rel_p;
    #pragma unroll
    for (int t = 0; t < 4; ++t) {
        int node = wave * 4 + t;
        if (node >= totalNodes) return;
        const float2 v = *(const float2*)(x + (size_t)node * DD + lane * 2);
        float pr = waveReduceSum(v.x * wr0 + v.y * wr1);
        float po = waveReduceSum(v.x * wo0 + v.y * wo1);
        if (lane == 0) { s_rel[node] = pr; attn[node] = po + brel; }
    }
}

// ---------------------------------------------------------------------------
// Kernel 2: layer-1 edge scatter, global fp32 atomics (attn array L2-resident)
// grid covers exactly NG*NE threads.
// ---------------------------------------------------------------------------
__global__ __launch_bounds__(256) void scatter1_kernel(
    const int* __restrict__ ei,          // (G, 2, E)
    const float* __restrict__ s_rel,     // (G*N0)
    float* __restrict__ attn)            // (G*N0)
{
    int e = blockIdx.x * 256 + threadIdx.x;
    int g = e >> 14, eo = e & (NE - 1);
    const int* base = ei + (size_t)g * 2 * NE;
    int s = base[eo], d = base[NE + eo];
    atomicAdd(&attn[(g << 10) + d], s_rel[(g << 10) + s]);
}

// ---------------------------------------------------------------------------
// Kernel 3/6: per-graph top-k. Register-resident hybrid bitonic sort:
// 1 thread = 1 element; j<=32 passes via __shfl_xor (no barriers),
// j>=64 passes via LDS. Key = (monotone(score) desc, index asc) — exact
// jax.lax.top_k tie semantics.
// ---------------------------------------------------------------------------
template<int NN, int KK>
__global__ __launch_bounds__(NN) void topk_kernel(
    const float* __restrict__ attn,      // (G*NN), fully-accumulated incl bias
    const float* __restrict__ w_sel_p,
    int*   __restrict__ permOut,         // (G, KK)
    float* __restrict__ topsOut,         // (G, KK)
    int*   __restrict__ newidxOut)       // (G, NN) or null
{
    __shared__ unsigned long long lds[NN];
    const int g = blockIdx.x, i = threadIdx.x;
    const float sgn = (*w_sel_p >= 0.f) ? 1.f : -1.f;

    float sc = tanhf(attn[(size_t)g * NN + i] * sgn);
    unsigned int u = __float_as_uint(sc);
    u = (u & 0x80000000u) ? ~u : (u | 0x80000000u);
    unsigned long long key =
        ((unsigned long long)u << 32) | (unsigned int)(NN - 1 - i);

    for (int k2 = 2; k2 <= NN; k2 <<= 1) {
        for (int j = k2 >> 1; j > 0; j >>= 1) {
            unsigned long long p;
            if (j >= 64) {
                __syncthreads();
                lds[i] = key;
                __syncthreads();
                p = lds[i ^ j];
            } else {
                p = __shfl_xor(key, j, 64);
            }
            // descending overall: segment desc when (i & k2)==0
            bool keepMax = (((i & k2) == 0) == ((i & j) == 0));
            if (keepMax ? (p > key) : (p < key)) key = p;
        }
    }

    // thread i now holds the rank-i key (descending)
    int idx = (NN - 1) - (int)(key & 0xffffffffu);
    unsigned int ku = (unsigned int)(key >> 32);
    unsigned int fb = (ku & 0x80000000u) ? (ku ^ 0x80000000u) : ~ku;
    if (i < KK) {
        permOut[(size_t)g * KK + i] = idx;
        topsOut[(size_t)g * KK + i] = __uint_as_float(fb);
    }
    if (newidxOut) newidxOut[(size_t)g * NN + idx] = (i < KK) ? i : -1;
}

// ---------------------------------------------------------------------------
// Kernel 4: layer-2 dots through perm1 (x1 never materialized).
// s_rel2[j] = tops1[j] * (x0[g,perm1[j]].w_rel2) ; attn2[j] likewise + b.
// ---------------------------------------------------------------------------
__global__ __launch_bounds__(256) void gdots2_kernel(
    const float* __restrict__ x0,        // (G, N0, D)
    const int*   __restrict__ perm1,     // (G, N1)
    const float* __restrict__ tops1,     // (G, N1)
    const float* __restrict__ w_rel, const float* __restrict__ w_root,
    const float* __restrict__ b_rel_p,
    float* __restrict__ s_rel2, float* __restrict__ attn2,
    int totalOut)
{
    int wave = blockIdx.x * 4 + (threadIdx.x >> 6);
    int lane = threadIdx.x & 63;
    float wr0 = w_rel[lane * 2],  wr1 = w_rel[lane * 2 + 1];
    float wo0 = w_root[lane * 2], wo1 = w_root[lane * 2 + 1];
    float brel = *b_rel_p;
    #pragma unroll
    for (int t = 0; t < 4; ++t) {
        int j = wave * 4 + t;
        if (j >= totalOut) return;
        int g = j >> 9;                       // /N1
        int node = perm1[j];
        float scl = tops1[j];
        const float2 v = *(const float2*)(x0 + ((size_t)(g << 10) + node) * DD + lane * 2);
        float pr = waveReduceSum(v.x * wr0 + v.y * wr1);
        float po = waveReduceSum(v.x * wo0 + v.y * wo1);
        if (lane == 0) { s_rel2[j] = scl * pr; attn2[j] = scl * po + brel; }
    }
}

// ---------------------------------------------------------------------------
// Kernel 5: fused edge-remap + layer-2 scatter. src2/dst2/mask2 never stored.
// ---------------------------------------------------------------------------
__global__ __launch_bounds__(256) void remap_scatter2_kernel(
    const int* __restrict__ ei,          // original (G, 2, E)
    const int* __restrict__ newidx1,     // (G*N0)
    const float* __restrict__ s_rel2,    // (G*N1)
    float* __restrict__ attn2)           // (G*N1)
{
    int e = blockIdx.x * 256 + threadIdx.x;
    int g = e >> 14, eo = e & (NE - 1);
    const int* base = ei + (size_t)g * 2 * NE;
    int s = base[eo], d = base[NE + eo];
    int s2 = newidx1[(g << 10) + s];
    int d2 = newidx1[(g << 10) + d];
    if ((s2 | d2) >= 0)                   // both >= 0
        atomicAdd(&attn2[(g << 9) + d2], s_rel2[(g << 9) + s2]);
}

// ---------------------------------------------------------------------------
// Kernel 7: readout through the COMPOSED permutation
// x2[j] = x0[g, perm1[perm2[j]]] * tops1[perm2[j]] * tops2[j]
// then concat(mean, max) @ W_lin + b_lin.
// ---------------------------------------------------------------------------
__global__ __launch_bounds__(512) void readout_kernel(
    const float* __restrict__ x0,        // (G, N0, D)
    const int*   __restrict__ perm1,     // (G, N1)
    const float* __restrict__ tops1,     // (G, N1)
    const int*   __restrict__ perm2,     // (G, 256)
    const float* __restrict__ tops2,     // (G, 256)
    const float* __restrict__ W_lin,     // (2D, OUT) row-major
    const float* __restrict__ b_lin,     // (OUT)
    float* __restrict__ out)             // (G, OUT)
{
    __shared__ float sm[4][DD], mm[4][DD], r[2 * DD];
    __shared__ float po[4][NOUT];
    const int g = blockIdx.x, tid = threadIdx.x;
    const int d = tid & (DD - 1), q = tid >> 7;   // q in 0..3, 64 rows each
    const int*   p2 = perm2 + (size_t)g * 256;
    const float* t2 = tops2 + (size_t)g * 256;
    const int*   p1 = perm1 + (size_t)g * N1;
    const float* t1 = tops1 + (size_t)g * N1;

    float sum = 0.f, mx = -3.0e38f;
    #pragma unroll 4
    for (int j = q * 64; j < q * 64 + 64; ++j) {
        int r1 = p2[j];
        float sc = t2[j] * t1[r1];
        int n0 = p1[r1];
        float v = x0[((size_t)(g << 10) + n0) * DD + d] * sc;
        sum += v;
        mx = fmaxf(mx, v);
    }
    sm[q][d] = sum; mm[q][d] = mx;
    __syncthreads();
    if (tid < DD) {
        r[tid] = (sm[0][tid] + sm[1][tid] + sm[2][tid] + sm[3][tid]) * (1.f / 256.f);
    } else if (tid < 2 * DD) {
        int dd = tid - DD;
        r[DD + dd] = fmaxf(fmaxf(mm[0][dd], mm[1][dd]), fmaxf(mm[2][dd], mm[3][dd]));
    }
    __syncthreads();
    if (tid < 256) {
        int o = tid & (NOUT - 1), c = tid >> 6;   // c in 0..3, 64 i's each
        float acc = 0.f;
        #pragma unroll
        for (int i2 = 0; i2 < 64; ++i2) {
            int i = c * 64 + i2;
            acc += r[i] * W_lin[i * NOUT + o];
        }
        po[c][o] = acc;
    }
    __syncthreads();
    if (tid < NOUT)
        out[(size_t)g * NOUT + tid] =
            b_lin[tid] + po[0][tid] + po[1][tid] + po[2][tid] + po[3][tid];
}

// ---------------------------------------------------------------------------
extern "C" void kernel_launch(void* const* d_in, const int* in_sizes, int n_in,
                              void* d_out, int out_size, void* d_ws, size_t ws_size,
                              hipStream_t stream)
{
    const float* x0     = (const float*)d_in[0];  // (G, 1024, 128)
    const int*   ei     = (const int*)  d_in[1];  // (G, 2, E)
    const float* w_rel  = (const float*)d_in[2];  // (2, 128)
    const float* b_rel  = (const float*)d_in[3];  // (2,)
    const float* w_root = (const float*)d_in[4];  // (2, 128)
    const float* w_sel  = (const float*)d_in[5];  // (2,)
    const float* W_lin  = (const float*)d_in[6];  // (256, 64)
    const float* b_lin  = (const float*)d_in[7];  // (64,)
    float* out = (float*)d_out;
    (void)in_sizes; (void)n_in; (void)out_size; (void)ws_size;

    char* ws = (char*)d_ws;
    size_t off = 0;
    auto alloc = [&](size_t bytes) -> void* {
        off = (off + 255) & ~(size_t)255;
        void* p = ws + off;
        off += bytes;
        return p;
    };

    float* s_rel1  = (float*)alloc((size_t)NG * N0 * 4);
    float* attn1   = (float*)alloc((size_t)NG * N0 * 4);
    int*   perm1   = (int*)  alloc((size_t)NG * N1 * 4);
    float* tops1   = (float*)alloc((size_t)NG * N1 * 4);
    int*   newidx1 = (int*)  alloc((size_t)NG * N0 * 4);
    float* s_rel2  = (float*)alloc((size_t)NG * N1 * 4);
    float* attn2   = (float*)alloc((size_t)NG * N1 * 4);
    int*   perm2   = (int*)  alloc((size_t)NG * 256 * 4);
    float* tops2   = (float*)alloc((size_t)NG * 256 * 4);

    // ---- Layer 1 ----
    dots1_kernel<<<(NG * N0) / 16, 256, 0, stream>>>(
        x0, w_rel, w_root, b_rel, s_rel1, attn1, NG * N0);

    scatter1_kernel<<<(NG * NE) / 256, 256, 0, stream>>>(ei, s_rel1, attn1);

    topk_kernel<N0, N1><<<NG, N0, 0, stream>>>(
        attn1, w_sel, perm1, tops1, newidx1);

    // ---- Layer 2 ----
    gdots2_kernel<<<(NG * N1) / 16, 256, 0, stream>>>(
        x0, perm1, tops1, w_rel + DD, w_root + DD, b_rel + 1,
        s_rel2, attn2, NG * N1);

    remap_scatter2_kernel<<<(NG * NE) / 256, 256, 0, stream>>>(
        ei, newidx1, s_rel2, attn2);

    topk_kernel<N1, 256><<<NG, N1, 0, stream>>>(
        attn2, w_sel + 1, perm2, tops2, /*newidxOut=*/nullptr);

    // ---- Readout ----
    readout_kernel<<<NG, 512, 0, stream>>>(
        x0, perm1, tops1, perm2, tops2, W_lin, b_lin, out);
}

// Round 8
// 162.262 us; speedup vs baseline: 1.9103x; 1.1944x over previous
//
#include <hip/hip_runtime.h>
#include <stdint.h>

#define NG   64      // graphs
#define N0   1024    // nodes layer 1
#define N1   512     // nodes layer 2 (k1)
#define K2   256     // k at layer 2
#define DD   128     // feature dim
#define NE   16384   // edges per graph
#define NOUT 64      // output dim

__device__ __forceinline__ float waveReduceSum(float v) {
    for (int off = 32; off > 0; off >>= 1) v += __shfl_xor(v, off, 64);
    return v;
}

// Hybrid bitonic sort, descending, 1 thread = 1 element.
// j<64 passes via shfl (no barriers), j>=64 via LDS (2 barriers each).
template<int NN>
__device__ __forceinline__ unsigned long long bitonic_desc(
    unsigned long long key, unsigned long long* lds, int i)
{
    for (int k2 = 2; k2 <= NN; k2 <<= 1) {
        for (int j = k2 >> 1; j > 0; j >>= 1) {
            unsigned long long p;
            if (j >= 64) {
                __syncthreads();
                lds[i] = key;
                __syncthreads();
                p = lds[i ^ j];
            } else {
                p = __shfl_xor(key, j, 64);
            }
            bool keepMax = (((i & k2) == 0) == ((i & j) == 0));
            if (keepMax ? (p > key) : (p < key)) key = p;
        }
    }
    return key;
}

__device__ __forceinline__ unsigned long long make_key(float attnv, float sgn, int i, int nn) {
    float sc = tanhf(attnv * sgn);
    unsigned int u = __float_as_uint(sc);
    u = (u & 0x80000000u) ? ~u : (u | 0x80000000u);
    return ((unsigned long long)u << 32) | (unsigned int)(nn - 1 - i);
}

// ---------------------------------------------------------------------------
// Kernel 1: per-node dots. s_rel[n] = x[n].w_rel ; attn[n] = x[n].w_root + b.
// ---------------------------------------------------------------------------
__global__ __launch_bounds__(256) void dots1_kernel(
    const float* __restrict__ x,
    const float* __restrict__ w_rel, const float* __restrict__ w_root,
    const float* __restrict__ b_rel_p,
    float* __restrict__ s_rel, float* __restrict__ attn,
    int totalNodes)
{
    int wave = blockIdx.x * 4 + (threadIdx.x >> 6);
    int lane = threadIdx.x & 63;
    float wr0 = w_rel[lane * 2],  wr1 = w_rel[lane * 2 + 1];
    float wo0 = w_root[lane * 2], wo1 = w_root[lane * 2 + 1];
    float brel = *b_rel_p;
    #pragma unroll
    for (int t = 0; t < 4; ++t) {
        int node = wave * 4 + t;
        if (node >= totalNodes) return;
        const float2 v = *(const float2*)(x + (size_t)node * DD + lane * 2);
        float pr = waveReduceSum(v.x * wr0 + v.y * wr1);
        float po = waveReduceSum(v.x * wo0 + v.y * wo1);
        if (lane == 0) { s_rel[node] = pr; attn[node] = po + brel; }
    }
}

// ---------------------------------------------------------------------------
// Kernel 2: layer-1 per-graph fused: LDS edge scatter + topk.
// One block of 1024 threads per graph.
// ---------------------------------------------------------------------------
__global__ __launch_bounds__(1024) void graph1_kernel(
    const float* __restrict__ s_rel1,    // (G*N0)
    const float* __restrict__ attn1in,   // (G*N0) incl root+bias
    const float* __restrict__ w_sel_p,
    const int*   __restrict__ ei,        // (G, 2, NE)
    int*   __restrict__ perm1,           // (G, N1)
    float* __restrict__ tops1,           // (G, N1)
    int*   __restrict__ newidx1)         // (G, N0)
{
    __shared__ float srel[N0];
    __shared__ float attn[N0];
    __shared__ unsigned long long keys[N0];
    const int g = blockIdx.x, i = threadIdx.x;

    srel[i] = s_rel1[(size_t)g * N0 + i];
    attn[i] = attn1in[(size_t)g * N0 + i];
    __syncthreads();

    const int* base = ei + (size_t)g * 2 * NE;
    #pragma unroll
    for (int it = 0; it < 4; ++it) {
        int eo = (it * 1024 + i) * 4;
        const int4 s4 = *(const int4*)(base + eo);
        const int4 d4 = *(const int4*)(base + NE + eo);
        atomicAdd(&attn[d4.x], srel[s4.x]);
        atomicAdd(&attn[d4.y], srel[s4.y]);
        atomicAdd(&attn[d4.z], srel[s4.z]);
        atomicAdd(&attn[d4.w], srel[s4.w]);
    }
    __syncthreads();

    const float sgn = (*w_sel_p >= 0.f) ? 1.f : -1.f;
    unsigned long long key = make_key(attn[i], sgn, i, N0);
    key = bitonic_desc<N0>(key, keys, i);

    int idx = (N0 - 1) - (int)(key & 0xffffffffu);
    unsigned int ku = (unsigned int)(key >> 32);
    unsigned int fb = (ku & 0x80000000u) ? (ku ^ 0x80000000u) : ~ku;
    if (i < N1) {
        perm1[(size_t)g * N1 + i] = idx;
        tops1[(size_t)g * N1 + i] = __uint_as_float(fb);
    }
    newidx1[(size_t)g * N0 + idx] = (i < N1) ? i : -1;
}

// ---------------------------------------------------------------------------
// Kernel 3: layer-2 dots through perm1 (x1 never materialized).
// ---------------------------------------------------------------------------
__global__ __launch_bounds__(256) void gdots2_kernel(
    const float* __restrict__ x0,        // (G, N0, D)
    const int*   __restrict__ perm1,     // (G, N1)
    const float* __restrict__ tops1,     // (G, N1)
    const float* __restrict__ w_rel, const float* __restrict__ w_root,
    const float* __restrict__ b_rel_p,
    float* __restrict__ s_rel2, float* __restrict__ attn2,
    int totalOut)
{
    int wave = blockIdx.x * 4 + (threadIdx.x >> 6);
    int lane = threadIdx.x & 63;
    float wr0 = w_rel[lane * 2],  wr1 = w_rel[lane * 2 + 1];
    float wo0 = w_root[lane * 2], wo1 = w_root[lane * 2 + 1];
    float brel = *b_rel_p;
    #pragma unroll
    for (int t = 0; t < 4; ++t) {
        int j = wave * 4 + t;
        if (j >= totalOut) return;
        int g = j >> 9;                       // /N1
        int node = perm1[j];
        float scl = tops1[j];
        const float2 v = *(const float2*)(x0 + ((size_t)(g << 10) + node) * DD + lane * 2);
        float pr = waveReduceSum(v.x * wr0 + v.y * wr1);
        float po = waveReduceSum(v.x * wo0 + v.y * wo1);
        if (lane == 0) { s_rel2[j] = scl * pr; attn2[j] = scl * po + brel; }
    }
}

// ---------------------------------------------------------------------------
// Kernel 4: layer-2 per-graph fused: remap + LDS scatter + topk + readout.
// One block of 512 threads per graph. perm2/tops2 never leave the block.
// ---------------------------------------------------------------------------
__global__ __launch_bounds__(512) void graph2_readout_kernel(
    const float* __restrict__ x0,        // (G, N0, D)
    const int*   __restrict__ ei,        // (G, 2, NE)
    const int*   __restrict__ newidx1,   // (G, N0)
    const int*   __restrict__ perm1,     // (G, N1)
    const float* __restrict__ tops1,     // (G, N1)
    const float* __restrict__ s_rel2,    // (G*N1)
    const float* __restrict__ attn2in,   // (G*N1) incl root+bias
    const float* __restrict__ w_sel_p,
    const float* __restrict__ W_lin,     // (2D, OUT)
    const float* __restrict__ b_lin,     // (OUT)
    float* __restrict__ out)             // (G, OUT)
{
    __shared__ int   nidx[N0];
    __shared__ float srel[N1];
    __shared__ float attn[N1];
    __shared__ unsigned long long keys[N1];
    __shared__ int   p1l[N1];
    __shared__ float t1l[N1];
    __shared__ int   cn0[K2];
    __shared__ float cs[K2];
    __shared__ float sm[4][DD], mm[4][DD], rr[2 * DD], po[4][NOUT];

    const int g = blockIdx.x, i = threadIdx.x;
    nidx[i]       = newidx1[(size_t)g * N0 + i];
    nidx[i + 512] = newidx1[(size_t)g * N0 + i + 512];
    srel[i] = s_rel2[(size_t)g * N1 + i];
    attn[i] = attn2in[(size_t)g * N1 + i];
    p1l[i]  = perm1[(size_t)g * N1 + i];
    t1l[i]  = tops1[(size_t)g * N1 + i];
    __syncthreads();

    const int* base = ei + (size_t)g * 2 * NE;
    #pragma unroll
    for (int it = 0; it < 8; ++it) {
        int eo = (it * 512 + i) * 4;
        const int4 s4 = *(const int4*)(base + eo);
        const int4 d4 = *(const int4*)(base + NE + eo);
        int s2, d2;
        s2 = nidx[s4.x]; d2 = nidx[d4.x]; if ((s2 | d2) >= 0) atomicAdd(&attn[d2], srel[s2]);
        s2 = nidx[s4.y]; d2 = nidx[d4.y]; if ((s2 | d2) >= 0) atomicAdd(&attn[d2], srel[s2]);
        s2 = nidx[s4.z]; d2 = nidx[d4.z]; if ((s2 | d2) >= 0) atomicAdd(&attn[d2], srel[s2]);
        s2 = nidx[s4.w]; d2 = nidx[d4.w]; if ((s2 | d2) >= 0) atomicAdd(&attn[d2], srel[s2]);
    }
    __syncthreads();

    const float sgn = (*w_sel_p >= 0.f) ? 1.f : -1.f;
    unsigned long long key = make_key(attn[i], sgn, i, N1);
    key = bitonic_desc<N1>(key, keys, i);

    int idx = (N1 - 1) - (int)(key & 0xffffffffu);
    unsigned int ku = (unsigned int)(key >> 32);
    unsigned int fb = (ku & 0x80000000u) ? (ku ^ 0x80000000u) : ~ku;
    if (i < K2) {
        // composed gather: node in x0 and total scale
        cn0[i] = p1l[idx];
        cs[i]  = __uint_as_float(fb) * t1l[idx];
    }
    __syncthreads();

    // readout: mean/max over 256 rows of x0[cn0[j]] * cs[j]
    const int d = i & (DD - 1), q = i >> 7;      // q in 0..3, 64 rows each
    float sum = 0.f, mx = -3.0e38f;
    #pragma unroll 4
    for (int j = q * 64; j < q * 64 + 64; ++j) {
        float v = x0[((size_t)(g << 10) + cn0[j]) * DD + d] * cs[j];
        sum += v;
        mx = fmaxf(mx, v);
    }
    sm[q][d] = sum; mm[q][d] = mx;
    __syncthreads();
    if (i < DD) {
        rr[i] = (sm[0][i] + sm[1][i] + sm[2][i] + sm[3][i]) * (1.f / 256.f);
    } else if (i < 2 * DD) {
        int dd = i - DD;
        rr[DD + dd] = fmaxf(fmaxf(mm[0][dd], mm[1][dd]), fmaxf(mm[2][dd], mm[3][dd]));
    }
    __syncthreads();
    if (i < 256) {
        int o = i & (NOUT - 1), c = i >> 6;      // c in 0..3
        float acc = 0.f;
        #pragma unroll
        for (int i2 = 0; i2 < 64; ++i2) {
            int ii = c * 64 + i2;
            acc += rr[ii] * W_lin[ii * NOUT + o];
        }
        po[c][o] = acc;
    }
    __syncthreads();
    if (i < NOUT)
        out[(size_t)g * NOUT + i] =
            b_lin[i] + po[0][i] + po[1][i] + po[2][i] + po[3][i];
}

// ---------------------------------------------------------------------------
extern "C" void kernel_launch(void* const* d_in, const int* in_sizes, int n_in,
                              void* d_out, int out_size, void* d_ws, size_t ws_size,
                              hipStream_t stream)
{
    const float* x0     = (const float*)d_in[0];  // (G, 1024, 128)
    const int*   ei     = (const int*)  d_in[1];  // (G, 2, E)
    const float* w_rel  = (const float*)d_in[2];  // (2, 128)
    const float* b_rel  = (const float*)d_in[3];  // (2,)
    const float* w_root = (const float*)d_in[4];  // (2, 128)
    const float* w_sel  = (const float*)d_in[5];  // (2,)
    const float* W_lin  = (const float*)d_in[6];  // (256, 64)
    const float* b_lin  = (const float*)d_in[7];  // (64,)
    float* out = (float*)d_out;
    (void)in_sizes; (void)n_in; (void)out_size; (void)ws_size;

    char* ws = (char*)d_ws;
    size_t off = 0;
    auto alloc = [&](size_t bytes) -> void* {
        off = (off + 255) & ~(size_t)255;
        void* p = ws + off;
        off += bytes;
        return p;
    };

    float* s_rel1  = (float*)alloc((size_t)NG * N0 * 4);
    float* attn1   = (float*)alloc((size_t)NG * N0 * 4);
    int*   perm1   = (int*)  alloc((size_t)NG * N1 * 4);
    float* tops1   = (float*)alloc((size_t)NG * N1 * 4);
    int*   newidx1 = (int*)  alloc((size_t)NG * N0 * 4);
    float* s_rel2  = (float*)alloc((size_t)NG * N1 * 4);
    float* attn2   = (float*)alloc((size_t)NG * N1 * 4);

    // ---- Layer 1 ----
    dots1_kernel<<<(NG * N0) / 16, 256, 0, stream>>>(
        x0, w_rel, w_root, b_rel, s_rel1, attn1, NG * N0);

    graph1_kernel<<<NG, 1024, 0, stream>>>(
        s_rel1, attn1, w_sel, ei, perm1, tops1, newidx1);

    // ---- Layer 2 ----
    gdots2_kernel<<<(NG * N1) / 16, 256, 0, stream>>>(
        x0, perm1, tops1, w_rel + DD, w_root + DD, b_rel + 1,
        s_rel2, attn2, NG * N1);

    graph2_readout_kernel<<<NG, 512, 0, stream>>>(
        x0, ei, newidx1, perm1, tops1, s_rel2, attn2, w_sel + 1,
        W_lin, b_lin, out);
}